// Round 1
// baseline (113.345 us; speedup 1.0000x reference)
//
#include <hip/hip_runtime.h>

#define NMODE 8
#define NPSI  512

// one thread per particle; 256 threads/block
__global__ void eik_kernel(
    const float* __restrict__ t_p,
    const float* __restrict__ r_p,
    const float* __restrict__ vp_p,
    const float* __restrict__ z_p,
    const float* __restrict__ psi_p,
    const float* __restrict__ ghre_p,
    const float* __restrict__ ghim_p,
    const float* __restrict__ a0tab_p,
    const float* __restrict__ iotatab_p,
    const float* __restrict__ psi0_p,
    const float* __restrict__ psisc_p,
    const float* __restrict__ alsc_p,
    const float* __restrict__ omega_p,
    const int*   __restrict__ nmode_p,
    float* __restrict__ out,
    int npart)
{
    constexpr float R0      = 1.7f;
    constexpr float TWO_PI  = 6.28318530717958647692f;
    constexpr float INV_2PI = 0.15915494309189533577f;
    constexpr float NHL2E   = -0.72134752044448170368f; // -0.5*log2(e)

    __shared__ float s_iota[NPSI];
    __shared__ float s_a0[NMODE][NPSI];   // transposed: [mode][psi] -> 4 taps contiguous
    __shared__ float s_md[NMODE][32];     // 0..11 re coefs (j*2+f), 12..23 im coefs,
                                          // 24 psi0, 25 1/psi_scale, 26 1/alpha_scale,
                                          // 27 omega*t, 28 (float)n

    const int tid = threadIdx.x;

    for (int p = tid; p < NPSI; p += 256) s_iota[p] = iotatab_p[p];
    for (int idx = tid; idx < NPSI * NMODE; idx += 256) {
        // input layout [psi][mode]; coalesced read, transposed write
        s_a0[idx & 7][idx >> 3] = a0tab_p[idx];
    }
    if (tid < NMODE * 12) {
        int m = tid / 12, j = tid - m * 12;
        s_md[m][j]      = ghre_p[m * 12 + j];
        s_md[m][12 + j] = ghim_p[m * 12 + j];
    }
    if (tid < NMODE) {
        s_md[tid][24] = psi0_p[tid];
        s_md[tid][25] = 1.0f / psisc_p[tid];
        s_md[tid][26] = 1.0f / alsc_p[tid];
        s_md[tid][27] = omega_p[tid] * t_p[0];
        s_md[tid][28] = (float)nmode_p[tid];
    }
    __syncthreads();

    const int i = blockIdx.x * 256 + tid;
    if (i >= npart) return;

    const float ps = psi_p[i];
    const float rr = r_p[i];
    const float zz = z_p[i];
    const float vp = vp_p[i];

    const float theta = atan2f(zz, rr - R0);

    // Catmull-Rom setup (uniform grid over [0,1], 512 pts)
    const float s = ps * (float)(NPSI - 1);
    int ii = (int)floorf(s);
    ii = ii < 1 ? 1 : (ii > NPSI - 3 ? NPSI - 3 : ii);
    const float tt = s - (float)ii;
    const float t2 = tt * tt, t3 = t2 * tt;
    const float wm1 = 0.5f * (-t3 + 2.0f * t2 - tt);
    const float w0  = 0.5f * (3.0f * t3 - 5.0f * t2 + 2.0f);
    const float w1  = 0.5f * (-3.0f * t3 + 4.0f * t2 + tt);
    const float w2  = 0.5f * (t3 - t2);

    const float iota = wm1 * s_iota[ii - 1] + w0 * s_iota[ii]
                     + w1 * s_iota[ii + 1] + w2 * s_iota[ii + 2];
    const float at      = iota * theta;     // alpha at k=1 (shift 0)
    const float dy_base = iota * TWO_PI;    // branch step in alpha

    float acc0 = 0.0f, acc1 = 0.0f;

    for (int m = 0; m < NMODE; ++m) {
        const float* md = s_md[m];
        const float a0 = wm1 * s_a0[m][ii - 1] + w0 * s_a0[m][ii]
                       + w1 * s_a0[m][ii + 1] + w2 * s_a0[m][ii + 2];
        const float x      = (ps - md[24]) * md[25];
        const float inv_as = md[26];
        const float ot     = md[27];
        const float nf     = md[28];

        const float xx    = x * x;
        const float h20   = 4.0f * xx - 2.0f;
        const float xterm = xx * NHL2E;
        const float base  = at - a0;                 // alpha(k=1) - alpha0
        const float y1    = base * inv_as;
        const float dy    = dy_base * inv_as;        // y step per branch
        // phase in revolutions: (omega*t - n*(varphi - base))/2pi; step = n*iota rev
        const float pcr = (ot - nf * (vp - base)) * INV_2PI;
        const float dpr = nf * iota;

        // k-invariant partial polynomials (c0 + c1*x + c3*h20), per field, re/im
        const float pxr0 = md[0]  + md[2]  * x + md[6]  * h20;
        const float pxr1 = md[1]  + md[3]  * x + md[7]  * h20;
        const float pxi0 = md[12] + md[14] * x + md[18] * h20;
        const float pxi1 = md[13] + md[15] * x + md[19] * h20;

        #pragma unroll
        for (int k = 0; k < 3; ++k) {
            const float kf  = (float)(k - 1);
            const float y   = fmaf(kf, dy,  y1);
            const float phr = fmaf(kf, dpr, pcr);
            const float yy  = y * y;
            const float g   = __builtin_amdgcn_exp2f(fmaf(yy, NHL2E, xterm));
            const float fr  = __builtin_amdgcn_fractf(phr);
            const float sn  = __builtin_amdgcn_sinf(fr);   // sin(2*pi*fr)
            const float cs  = __builtin_amdgcn_cosf(fr);   // cos(2*pi*fr)
            const float h11 = x * y;
            const float h02 = fmaf(4.0f, yy, -2.0f);

            const float pr0 = pxr0 + md[4]  * y + md[8]  * h11 + md[10] * h02;
            const float pr1 = pxr1 + md[5]  * y + md[9]  * h11 + md[11] * h02;
            const float pi0 = pxi0 + md[16] * y + md[20] * h11 + md[22] * h02;
            const float pi1 = pxi1 + md[17] * y + md[21] * h11 + md[23] * h02;

            const float gc = g * cs;
            const float gs = g * sn;
            acc0 = fmaf(pr0, gc, acc0);
            acc0 = fmaf(pi0, -gs, acc0);
            acc1 = fmaf(pr1, gc, acc1);
            acc1 = fmaf(pi1, -gs, acc1);
        }
    }

    reinterpret_cast<float2*>(out)[i] = make_float2(acc0, acc1);
}

extern "C" void kernel_launch(void* const* d_in, const int* in_sizes, int n_in,
                              void* d_out, int out_size, void* d_ws, size_t ws_size,
                              hipStream_t stream) {
    const float* t      = (const float*)d_in[0];
    const float* r      = (const float*)d_in[1];
    const float* varphi = (const float*)d_in[2];
    const float* z      = (const float*)d_in[3];
    const float* psi    = (const float*)d_in[4];
    const float* gh_re  = (const float*)d_in[5];
    const float* gh_im  = (const float*)d_in[6];
    const float* a0t    = (const float*)d_in[7];
    const float* iot    = (const float*)d_in[8];
    const float* psi0   = (const float*)d_in[9];
    const float* psc    = (const float*)d_in[10];
    const float* asc    = (const float*)d_in[11];
    const float* omg    = (const float*)d_in[12];
    const int*   nn     = (const int*)d_in[13];
    float* out = (float*)d_out;

    const int npart  = in_sizes[1];
    const int blocks = (npart + 255) / 256;
    eik_kernel<<<blocks, 256, 0, stream>>>(t, r, varphi, z, psi, gh_re, gh_im,
                                           a0t, iot, psi0, psc, asc, omg, nn,
                                           out, npart);
}

// Round 2
// 99.183 us; speedup vs baseline: 1.1428x; 1.1428x over previous
//
#include <hip/hip_runtime.h>

#define NMODE 8
#define NPSI  512

// 2 particles per thread; 256 threads/block; grid = (N/2)/256 blocks.
// Per-mode constants are wave-uniform -> read straight from global (SMEM/SGPR),
// LDS holds only the per-lane-gathered interpolation tables.
__global__ __launch_bounds__(256) void eik_kernel(
    const float* __restrict__ t_p,
    const float* __restrict__ r_p,
    const float* __restrict__ vp_p,
    const float* __restrict__ z_p,
    const float* __restrict__ psi_p,
    const float* __restrict__ ghre_p,
    const float* __restrict__ ghim_p,
    const float* __restrict__ a0tab_p,
    const float* __restrict__ iotatab_p,
    const float* __restrict__ psi0_p,
    const float* __restrict__ psisc_p,
    const float* __restrict__ alsc_p,
    const float* __restrict__ omega_p,
    const int*   __restrict__ nmode_p,
    float* __restrict__ out,
    int npart)
{
    constexpr float R0      = 1.7f;
    constexpr float TWO_PI  = 6.28318530717958647692f;
    constexpr float INV_2PI = 0.15915494309189533577f;
    constexpr float NHL2E   = -0.72134752044448170368f; // -0.5*log2(e)

    __shared__ float s_iota[NPSI];
    __shared__ float s_a0[NMODE][NPSI];   // [mode][psi]: 4 interp taps contiguous

    const int tid = threadIdx.x;
    for (int p = tid; p < NPSI; p += 256) s_iota[p] = iotatab_p[p];
    for (int idx = tid; idx < NPSI * NMODE; idx += 256)
        s_a0[idx & 7][idx >> 3] = a0tab_p[idx];   // coalesced read, transposed write
    __syncthreads();

    const int half = npart >> 1;
    const int i0 = blockIdx.x * 256 + tid;
    if (i0 >= half) return;
    const int i1 = i0 + half;

    const float tval = t_p[0];

    const float psA = psi_p[i0];
    const float psB = psi_p[i1];
    const float thA = atan2f(z_p[i0], r_p[i0] - R0);
    const float thB = atan2f(z_p[i1], r_p[i1] - R0);
    const float vpA = vp_p[i0];
    const float vpB = vp_p[i1];

    // Catmull-Rom setup (uniform grid over [0,1], 512 pts), per particle
    float sA = psA * (float)(NPSI - 1);
    int iiA = (int)floorf(sA);
    iiA = iiA < 1 ? 1 : (iiA > NPSI - 3 ? NPSI - 3 : iiA);
    const float ttA = sA - (float)iiA;
    const float tA2 = ttA * ttA, tA3 = tA2 * ttA;
    const float wAm1 = 0.5f * (-tA3 + 2.0f * tA2 - ttA);
    const float wA0  = 0.5f * (3.0f * tA3 - 5.0f * tA2 + 2.0f);
    const float wA1  = 0.5f * (-3.0f * tA3 + 4.0f * tA2 + ttA);
    const float wA2  = 0.5f * (tA3 - tA2);

    float sB = psB * (float)(NPSI - 1);
    int iiB = (int)floorf(sB);
    iiB = iiB < 1 ? 1 : (iiB > NPSI - 3 ? NPSI - 3 : iiB);
    const float ttB = sB - (float)iiB;
    const float tB2 = ttB * ttB, tB3 = tB2 * ttB;
    const float wBm1 = 0.5f * (-tB3 + 2.0f * tB2 - ttB);
    const float wB0  = 0.5f * (3.0f * tB3 - 5.0f * tB2 + 2.0f);
    const float wB1  = 0.5f * (-3.0f * tB3 + 4.0f * tB2 + ttB);
    const float wB2  = 0.5f * (tB3 - tB2);

    const float iotaA = wAm1 * s_iota[iiA - 1] + wA0 * s_iota[iiA]
                      + wA1 * s_iota[iiA + 1] + wA2 * s_iota[iiA + 2];
    const float iotaB = wBm1 * s_iota[iiB - 1] + wB0 * s_iota[iiB]
                      + wB1 * s_iota[iiB + 1] + wB2 * s_iota[iiB + 2];

    const float atA  = iotaA * thA;      // alpha at k=1 (shift 0)
    const float atB  = iotaB * thB;
    const float dybA = iotaA * TWO_PI;   // branch step in alpha
    const float dybB = iotaB * TWO_PI;

    float acc00 = 0.0f, acc01 = 0.0f;    // particle A: field 0, 1
    float acc10 = 0.0f, acc11 = 0.0f;    // particle B: field 0, 1

    for (int m = 0; m < NMODE; ++m) {
        // ---- wave-uniform constants: SMEM path, zero vector-pipe cost ----
        const float c0r0 = ghre_p[m*12+ 0], c0r1 = ghre_p[m*12+ 1];
        const float c1r0 = ghre_p[m*12+ 2], c1r1 = ghre_p[m*12+ 3];
        const float c2r0 = ghre_p[m*12+ 4], c2r1 = ghre_p[m*12+ 5];
        const float c3r0 = ghre_p[m*12+ 6], c3r1 = ghre_p[m*12+ 7];
        const float c4r0 = ghre_p[m*12+ 8], c4r1 = ghre_p[m*12+ 9];
        const float c5r0 = ghre_p[m*12+10], c5r1 = ghre_p[m*12+11];
        const float c0i0 = ghim_p[m*12+ 0], c0i1 = ghim_p[m*12+ 1];
        const float c1i0 = ghim_p[m*12+ 2], c1i1 = ghim_p[m*12+ 3];
        const float c2i0 = ghim_p[m*12+ 4], c2i1 = ghim_p[m*12+ 5];
        const float c3i0 = ghim_p[m*12+ 6], c3i1 = ghim_p[m*12+ 7];
        const float c4i0 = ghim_p[m*12+ 8], c4i1 = ghim_p[m*12+ 9];
        const float c5i0 = ghim_p[m*12+10], c5i1 = ghim_p[m*12+11];
        const float psi0m = psi0_p[m];
        const float ipsc  = __builtin_amdgcn_rcpf(psisc_p[m]);
        const float iasc  = __builtin_amdgcn_rcpf(alsc_p[m]);
        const float ot    = omega_p[m] * tval;
        const float nf    = (float)nmode_p[m];

        const float* row = s_a0[m];

        // ================= particle A =================
        {
            const float a0 = wAm1 * row[iiA - 1] + wA0 * row[iiA]
                           + wA1 * row[iiA + 1] + wA2 * row[iiA + 2];
            const float x     = (psA - psi0m) * ipsc;
            const float xx    = x * x;
            const float h20   = fmaf(4.0f, xx, -2.0f);
            const float xterm = xx * NHL2E;
            const float base  = atA - a0;
            const float y1    = base * iasc;
            const float dy    = dybA * iasc;
            const float pcr   = (ot - nf * (vpA - base)) * INV_2PI;
            const float dpr   = nf * iotaA;

            const float pxr0 = fmaf(c3r0, h20, fmaf(c1r0, x, c0r0));
            const float pxr1 = fmaf(c3r1, h20, fmaf(c1r1, x, c0r1));
            const float pxi0 = fmaf(c3i0, h20, fmaf(c1i0, x, c0i0));
            const float pxi1 = fmaf(c3i1, h20, fmaf(c1i1, x, c0i1));
            const float er0  = fmaf(c4r0, x, c2r0);
            const float er1  = fmaf(c4r1, x, c2r1);
            const float ei0  = fmaf(c4i0, x, c2i0);
            const float ei1  = fmaf(c4i1, x, c2i1);

            #pragma unroll
            for (int k = 0; k < 3; ++k) {
                const float kf  = (float)(k - 1);
                const float y   = fmaf(kf, dy, y1);
                const float phr = fmaf(kf, dpr, pcr);
                const float yy  = y * y;
                const float g   = __builtin_amdgcn_exp2f(fmaf(yy, NHL2E, xterm));
                const float fr  = __builtin_amdgcn_fractf(phr);
                const float sn  = __builtin_amdgcn_sinf(fr);
                const float cs  = __builtin_amdgcn_cosf(fr);
                const float h02 = fmaf(4.0f, yy, -2.0f);
                const float pr0 = fmaf(c5r0, h02, fmaf(er0, y, pxr0));
                const float pr1 = fmaf(c5r1, h02, fmaf(er1, y, pxr1));
                const float pi0 = fmaf(c5i0, h02, fmaf(ei0, y, pxi0));
                const float pi1 = fmaf(c5i1, h02, fmaf(ei1, y, pxi1));
                const float gc = g * cs;
                const float gs = g * sn;
                acc00 = fmaf(pr0, gc, acc00); acc00 = fmaf(pi0, -gs, acc00);
                acc01 = fmaf(pr1, gc, acc01); acc01 = fmaf(pi1, -gs, acc01);
            }
        }

        // ================= particle B =================
        {
            const float a0 = wBm1 * row[iiB - 1] + wB0 * row[iiB]
                           + wB1 * row[iiB + 1] + wB2 * row[iiB + 2];
            const float x     = (psB - psi0m) * ipsc;
            const float xx    = x * x;
            const float h20   = fmaf(4.0f, xx, -2.0f);
            const float xterm = xx * NHL2E;
            const float base  = atB - a0;
            const float y1    = base * iasc;
            const float dy    = dybB * iasc;
            const float pcr   = (ot - nf * (vpB - base)) * INV_2PI;
            const float dpr   = nf * iotaB;

            const float pxr0 = fmaf(c3r0, h20, fmaf(c1r0, x, c0r0));
            const float pxr1 = fmaf(c3r1, h20, fmaf(c1r1, x, c0r1));
            const float pxi0 = fmaf(c3i0, h20, fmaf(c1i0, x, c0i0));
            const float pxi1 = fmaf(c3i1, h20, fmaf(c1i1, x, c0i1));
            const float er0  = fmaf(c4r0, x, c2r0);
            const float er1  = fmaf(c4r1, x, c2r1);
            const float ei0  = fmaf(c4i0, x, c2i0);
            const float ei1  = fmaf(c4i1, x, c2i1);

            #pragma unroll
            for (int k = 0; k < 3; ++k) {
                const float kf  = (float)(k - 1);
                const float y   = fmaf(kf, dy, y1);
                const float phr = fmaf(kf, dpr, pcr);
                const float yy  = y * y;
                const float g   = __builtin_amdgcn_exp2f(fmaf(yy, NHL2E, xterm));
                const float fr  = __builtin_amdgcn_fractf(phr);
                const float sn  = __builtin_amdgcn_sinf(fr);
                const float cs  = __builtin_amdgcn_cosf(fr);
                const float h02 = fmaf(4.0f, yy, -2.0f);
                const float pr0 = fmaf(c5r0, h02, fmaf(er0, y, pxr0));
                const float pr1 = fmaf(c5r1, h02, fmaf(er1, y, pxr1));
                const float pi0 = fmaf(c5i0, h02, fmaf(ei0, y, pxi0));
                const float pi1 = fmaf(c5i1, h02, fmaf(ei1, y, pxi1));
                const float gc = g * cs;
                const float gs = g * sn;
                acc10 = fmaf(pr0, gc, acc10); acc10 = fmaf(pi0, -gs, acc10);
                acc11 = fmaf(pr1, gc, acc11); acc11 = fmaf(pi1, -gs, acc11);
            }
        }
    }

    reinterpret_cast<float2*>(out)[i0] = make_float2(acc00, acc01);
    reinterpret_cast<float2*>(out)[i1] = make_float2(acc10, acc11);
}

extern "C" void kernel_launch(void* const* d_in, const int* in_sizes, int n_in,
                              void* d_out, int out_size, void* d_ws, size_t ws_size,
                              hipStream_t stream) {
    const float* t      = (const float*)d_in[0];
    const float* r      = (const float*)d_in[1];
    const float* varphi = (const float*)d_in[2];
    const float* z      = (const float*)d_in[3];
    const float* psi    = (const float*)d_in[4];
    const float* gh_re  = (const float*)d_in[5];
    const float* gh_im  = (const float*)d_in[6];
    const float* a0t    = (const float*)d_in[7];
    const float* iot    = (const float*)d_in[8];
    const float* psi0   = (const float*)d_in[9];
    const float* psc    = (const float*)d_in[10];
    const float* asc    = (const float*)d_in[11];
    const float* omg    = (const float*)d_in[12];
    const int*   nn     = (const int*)d_in[13];
    float* out = (float*)d_out;

    const int npart = in_sizes[1];
    const int half  = npart >> 1;
    const int blocks = (half + 255) / 256;
    eik_kernel<<<blocks, 256, 0, stream>>>(t, r, varphi, z, psi, gh_re, gh_im,
                                           a0t, iot, psi0, psc, asc, omg, nn,
                                           out, npart);
}

// Round 5
// 96.879 us; speedup vs baseline: 1.1700x; 1.0238x over previous
//
#include <hip/hip_runtime.h>

#define NMODE   8
#define NPSI    512
#define RSTRIDE 12   // 8 a0 modes + iota + 3 pad; 48B rows: 16B-aligned quads, stride-12 bank spread

// 1 particle per thread; 256 threads/block; 2048 blocks.
// Per-mode constants -> scalar loads (SGPR). LDS holds one packed table:
// s_pack[psi][0..7]=a0[mode], [8]=iota. A particle's whole gather is
// 4 rows x (2x ds_read_b128 + 1x ds_read_b32).
__global__ __launch_bounds__(256, 4) void eik_kernel(
    const float* __restrict__ t_p,
    const float* __restrict__ r_p,
    const float* __restrict__ vp_p,
    const float* __restrict__ z_p,
    const float* __restrict__ psi_p,
    const float* __restrict__ ghre_p,
    const float* __restrict__ ghim_p,
    const float* __restrict__ a0tab_p,
    const float* __restrict__ iotatab_p,
    const float* __restrict__ psi0_p,
    const float* __restrict__ psisc_p,
    const float* __restrict__ alsc_p,
    const float* __restrict__ omega_p,
    const int*   __restrict__ nmode_p,
    float* __restrict__ out,
    int npart)
{
    constexpr float R0      = 1.7f;
    constexpr float TWO_PI  = 6.28318530717958647692f;
    constexpr float INV_2PI = 0.15915494309189533577f;
    constexpr float NHL2E   = -0.72134752044448170368f; // -0.5*log2(e)

    __shared__ float s_pack[NPSI][RSTRIDE];

    const int tid = threadIdx.x;
    const int i   = blockIdx.x * 256 + tid;
    const bool live = (i < npart);

    // ---- independent per-particle work first (hides staging latency) ----
    float ps = 0.f, th = 0.f, vp = 0.f;
    if (live) {
        ps = psi_p[i];
        th = atan2f(z_p[i], r_p[i] - R0);
        vp = vp_p[i];
    }

    // Catmull-Rom setup (uniform grid over [0,1], 512 pts)
    const float s = ps * (float)(NPSI - 1);
    int ii = (int)floorf(s);
    ii = ii < 1 ? 1 : (ii > NPSI - 3 ? NPSI - 3 : ii);
    const float tt = s - (float)ii;
    const float t2 = tt * tt, t3 = t2 * tt;
    float w[4];
    w[0] = 0.5f * (-t3 + 2.0f * t2 - tt);
    w[1] = 0.5f * (3.0f * t3 - 5.0f * t2 + 2.0f);
    w[2] = 0.5f * (-3.0f * t3 + 4.0f * t2 + tt);
    w[3] = 0.5f * (t3 - t2);

    // ---- stage packed table: conflict-free writes, coalesced reads ----
    for (int p = tid; p < NPSI; p += 256) {
        const float4* src = reinterpret_cast<const float4*>(a0tab_p + p * 8);
        const float4 lo = src[0];
        const float4 hi = src[1];
        const float  io = iotatab_p[p];
        float* dst = s_pack[p];
        *reinterpret_cast<float4*>(dst)     = lo;
        *reinterpret_cast<float4*>(dst + 4) = hi;
        dst[8] = io;
    }
    __syncthreads();

    if (!live) return;

    // ---- one gather pass: all 8 a0's + iota via cubic interp ----
    float a0v[NMODE];
    #pragma unroll
    for (int q = 0; q < NMODE; ++q) a0v[q] = 0.0f;
    float iotv = 0.0f;

    #pragma unroll
    for (int j = 0; j < 4; ++j) {
        const float* rowp = s_pack[ii - 1 + j];
        const float4 lo = *reinterpret_cast<const float4*>(rowp);
        const float4 hi = *reinterpret_cast<const float4*>(rowp + 4);
        const float  io = rowp[8];
        const float  wj = w[j];
        a0v[0] = fmaf(wj, lo.x, a0v[0]);
        a0v[1] = fmaf(wj, lo.y, a0v[1]);
        a0v[2] = fmaf(wj, lo.z, a0v[2]);
        a0v[3] = fmaf(wj, lo.w, a0v[3]);
        a0v[4] = fmaf(wj, hi.x, a0v[4]);
        a0v[5] = fmaf(wj, hi.y, a0v[5]);
        a0v[6] = fmaf(wj, hi.z, a0v[6]);
        a0v[7] = fmaf(wj, hi.w, a0v[7]);
        iotv   = fmaf(wj, io,   iotv);
    }

    const float tval = t_p[0];
    const float at   = iotv * th;       // alpha at center branch (shift 0)
    const float dyb  = iotv * TWO_PI;   // branch step in alpha

    float acc0 = 0.0f, acc1 = 0.0f;

    #pragma unroll
    for (int m = 0; m < NMODE; ++m) {
        // wave-uniform constants: scalar-memory path
        const float c0r0 = ghre_p[m*12+ 0], c0r1 = ghre_p[m*12+ 1];
        const float c1r0 = ghre_p[m*12+ 2], c1r1 = ghre_p[m*12+ 3];
        const float c2r0 = ghre_p[m*12+ 4], c2r1 = ghre_p[m*12+ 5];
        const float c3r0 = ghre_p[m*12+ 6], c3r1 = ghre_p[m*12+ 7];
        const float c4r0 = ghre_p[m*12+ 8], c4r1 = ghre_p[m*12+ 9];
        const float c5r0 = ghre_p[m*12+10], c5r1 = ghre_p[m*12+11];
        const float c0i0 = ghim_p[m*12+ 0], c0i1 = ghim_p[m*12+ 1];
        const float c1i0 = ghim_p[m*12+ 2], c1i1 = ghim_p[m*12+ 3];
        const float c2i0 = ghim_p[m*12+ 4], c2i1 = ghim_p[m*12+ 5];
        const float c3i0 = ghim_p[m*12+ 6], c3i1 = ghim_p[m*12+ 7];
        const float c4i0 = ghim_p[m*12+ 8], c4i1 = ghim_p[m*12+ 9];
        const float c5i0 = ghim_p[m*12+10], c5i1 = ghim_p[m*12+11];
        const float psi0m = psi0_p[m];
        const float ipsc  = __builtin_amdgcn_rcpf(psisc_p[m]);
        const float iasc  = __builtin_amdgcn_rcpf(alsc_p[m]);
        const float ot    = omega_p[m] * tval;
        const float nf    = (float)nmode_p[m];

        const float a0    = a0v[m];
        const float x     = (ps - psi0m) * ipsc;
        const float xx    = x * x;
        const float h20   = fmaf(4.0f, xx, -2.0f);
        const float xterm = xx * NHL2E;
        const float base  = at - a0;
        const float y1    = base * iasc;
        const float dy    = dyb * iasc;
        const float pcr   = (ot - nf * (vp - base)) * INV_2PI;  // phase, revolutions
        const float dpr   = nf * iotv;                          // branch phase step, rev

        const float pxr0 = fmaf(c3r0, h20, fmaf(c1r0, x, c0r0));
        const float pxr1 = fmaf(c3r1, h20, fmaf(c1r1, x, c0r1));
        const float pxi0 = fmaf(c3i0, h20, fmaf(c1i0, x, c0i0));
        const float pxi1 = fmaf(c3i1, h20, fmaf(c1i1, x, c0i1));
        const float er0  = fmaf(c4r0, x, c2r0);
        const float er1  = fmaf(c4r1, x, c2r1);
        const float ei0  = fmaf(c4i0, x, c2i0);
        const float ei1  = fmaf(c4i1, x, c2i1);

        #pragma unroll
        for (int k = 0; k < 3; ++k) {
            const float kf  = (float)(k - 1);
            const float y   = fmaf(kf, dy, y1);
            const float phr = fmaf(kf, dpr, pcr);
            const float yy  = y * y;
            const float g   = __builtin_amdgcn_exp2f(fmaf(yy, NHL2E, xterm));
            const float fr  = __builtin_amdgcn_fractf(phr);
            const float sn  = __builtin_amdgcn_sinf(fr);   // sin(2*pi*fr)
            const float cs  = __builtin_amdgcn_cosf(fr);   // cos(2*pi*fr)
            const float h02 = fmaf(4.0f, yy, -2.0f);
            const float pr0 = fmaf(c5r0, h02, fmaf(er0, y, pxr0));
            const float pr1 = fmaf(c5r1, h02, fmaf(er1, y, pxr1));
            const float pi0 = fmaf(c5i0, h02, fmaf(ei0, y, pxi0));
            const float pi1 = fmaf(c5i1, h02, fmaf(ei1, y, pxi1));
            const float gc = g * cs;
            const float gs = g * sn;
            acc0 = fmaf(pr0, gc, acc0); acc0 = fmaf(pi0, -gs, acc0);
            acc1 = fmaf(pr1, gc, acc1); acc1 = fmaf(pi1, -gs, acc1);
        }
    }

    reinterpret_cast<float2*>(out)[i] = make_float2(acc0, acc1);
}

extern "C" void kernel_launch(void* const* d_in, const int* in_sizes, int n_in,
                              void* d_out, int out_size, void* d_ws, size_t ws_size,
                              hipStream_t stream) {
    const float* t      = (const float*)d_in[0];
    const float* r      = (const float*)d_in[1];
    const float* varphi = (const float*)d_in[2];
    const float* z      = (const float*)d_in[3];
    const float* psi    = (const float*)d_in[4];
    const float* gh_re  = (const float*)d_in[5];
    const float* gh_im  = (const float*)d_in[6];
    const float* a0t    = (const float*)d_in[7];
    const float* iot    = (const float*)d_in[8];
    const float* psi0   = (const float*)d_in[9];
    const float* psc    = (const float*)d_in[10];
    const float* asc    = (const float*)d_in[11];
    const float* omg    = (const float*)d_in[12];
    const int*   nn     = (const int*)d_in[13];
    float* out = (float*)d_out;

    const int npart  = in_sizes[1];
    const int blocks = (npart + 255) / 256;
    eik_kernel<<<blocks, 256, 0, stream>>>(t, r, varphi, z, psi, gh_re, gh_im,
                                           a0t, iot, psi0, psc, asc, omg, nn,
                                           out, npart);
}